// Round 18
// baseline (78.802 us; speedup 1.0000x reference)
//
#include <hip/hip_runtime.h>

#define NH   8192
#define DIM  256
#define NTOT 16384
#define TM   256                  // tile rows
#define TN   128                  // tile cols
#define NRB  64                   // row blocks
// kept tiles: C >= 2R; F(R) = R*(129-R); total = 4160
#define NTILES 4160
#define FCUM(R) ((R) * (129 - (R)))

constexpr float GAMMA = 0.00390625f; // 1/256
constexpr float QSCL  = 6.0f / 127.0f;   // i8 quant scale: x ~ q * QSCL

using i32x4 = __attribute__((ext_vector_type(4))) int;
using f32x4 = __attribute__((ext_vector_type(4))) float;

// ---------------- fused quantize (fp32 -> i8, s=6/127) + exact fp32 row norms ----------------
__global__ void prep_kernel(const float* __restrict__ zs,
                            const float* __restrict__ zt,
                            signed char* __restrict__ Zq,
                            float* __restrict__ n2) {
    int w = threadIdx.x >> 6, l = threadIdx.x & 63;
    int row = blockIdx.x * 4 + w;
    const float* zp = (row < NH) ? zs + (size_t)row * DIM
                                 : zt + (size_t)(row - NH) * DIM;
    float4 v = *(const float4*)(zp + l * 4);
    float s = v.x * v.x + v.y * v.y + v.z * v.z + v.w * v.w;
#pragma unroll
    for (int off = 32; off; off >>= 1) s += __shfl_xor(s, off);
    if (l == 0) n2[row] = s;

    const float inv = 127.0f / 6.0f;
    float x[4] = {v.x, v.y, v.z, v.w};
    int pk = 0;
#pragma unroll
    for (int j = 0; j < 4; ++j) {
        int q = (int)rintf(fminf(fmaxf(x[j] * inv, -127.0f), 127.0f));
        pk |= (q & 0xFF) << (8 * j);
    }
    *(int*)(Zq + (size_t)row * DIM + l * 4) = pk;
}

// ---------------- main: 256x128 tiles, 4 waves, i8 MFMA (16x16x64) ----------------
// ONE barrier per tile: whole A tile (64 KB) staged to LDS upfront; B fragments loaded
// straight from global (L2-resident) into registers, depth-2 rotation. Chunk loop is a
// barrier-free straight-line burst — compiler schedules ds_read/MFMA/B-wait interleave.
__global__ __launch_bounds__(256, 2)
void mmd_mfma_kernel(const signed char* __restrict__ Zq,
                     const float* __restrict__ n2,
                     double* __restrict__ partial) {
    // A tile: 4 K-slabs x 256 rows x 64 B = 64 KB
    __shared__ __align__(16) unsigned char lds[65536];

    const int tid = threadIdx.x;
    const int w = tid >> 6, l = tid & 63;
    const int wr = w >> 1, wc = w & 1;   // 2x2 wave grid; wave owns 128x64
    const int fr = l & 15;               // fragment row/col within 16
    const int g  = l >> 4;               // k-group 0..3

    // XCD-aware bijective swizzle (4160 % 8 == 0)
    int t = ((int)blockIdx.x & 7) * (NTILES / 8) + ((int)blockIdx.x >> 3);

    // t -> (R, C): largest R with F(R) <= t ; C = 2R + (t - F(R))
    int R = (int)((129.0 - sqrt(129.0 * 129.0 - 4.0 * (double)t)) * 0.5);
    if (R < 0) R = 0;
    if (R > NRB - 1) R = NRB - 1;
    while (R < NRB - 1 && FCUM(R + 1) <= t) ++R;
    while (R > 0 && FCUM(R) > t) --R;
    const int C = 2 * R + (t - FCUM(R));
    const int xbase = R * TM, ybase = C * TN;
    const bool straddle = (C <= 2 * R + 1);  // tile touches/crosses the diagonal

    const signed char* gA = Zq + (size_t)xbase * DIM;
    const signed char* gB = Zq + (size_t)ybase * DIM;

    // A fragment reads (bytes): slot' = g ^ ((fr>>1)&3)  (verified conflict-free R2..R17)
    const int slotp = g ^ ((fr >> 1) & 3);
    const int aoff = (wr * 128 + fr) * 64 + slotp * 16;   // + ch*16384 + m*1024

    // B global fragment byte offsets per n: row (ybase + wc*64 + n*16 + fr), k-group g
    const signed char* gBr[4];
#pragma unroll
    for (int n = 0; n < 4; ++n)
        gBr[n] = gB + (size_t)(wc * 64 + n * 16 + fr) * DIM + g * 16;

    i32x4 acc[8][4];
#pragma unroll
    for (int m = 0; m < 8; ++m)
#pragma unroll
        for (int n = 0; n < 4; ++n) acc[m][n] = {0, 0, 0, 0};

    // ---- prologue: stage ENTIRE A tile (16 global_load_lds), then 8 B loads ----
#pragma unroll
    for (int ch = 0; ch < 4; ++ch) {
#pragma unroll
        for (int q = 0; q < 4; ++q) {  // 1024 x 16B per slab
            const int idx = q * 256 + tid;
            const int row = idx >> 2;
            const int slot = (idx & 3) ^ ((row >> 1) & 3);
            const signed char* src = gA + (size_t)row * DIM + ch * 64 + slot * 16;
            __builtin_amdgcn_global_load_lds(src, &lds[ch * 16384 + idx * 16], 16, 0, 0);
        }
    }
    asm volatile("" ::: "memory");  // pin: B loads issue AFTER the 16 A stages

    i32x4 bqA[4], bqB[4];
#pragma unroll
    for (int n = 0; n < 4; ++n) bqA[n] = *(const i32x4*)(gBr[n] + 0 * 64);
#pragma unroll
    for (int n = 0; n < 4; ++n) bqB[n] = *(const i32x4*)(gBr[n] + 1 * 64);
    asm volatile("" ::: "memory");  // pin: wait counts below assume this issue order

    asm volatile("s_waitcnt vmcnt(8)" ::: "memory");  // 16 A stages retired; 8 B may fly
    __builtin_amdgcn_s_barrier();   // the ONLY barrier in the tile compute

    // ---- 4 chunks, barrier-free; B depth-2 rotation (consume then reload +2) ----
#define CHUNK(CH, BQ, RELOAD)                                                         \
    {                                                                                 \
        __builtin_amdgcn_s_setprio(1);                                                \
        _Pragma("unroll")                                                             \
        for (int m = 0; m < 8; ++m) {                                                 \
            i32x4 aq = *(const i32x4*)&lds[(CH) * 16384 + aoff + m * 1024];           \
            _Pragma("unroll")                                                         \
            for (int n = 0; n < 4; ++n)                                               \
                acc[m][n] = __builtin_amdgcn_mfma_i32_16x16x64_i8(aq, BQ[n], acc[m][n], 0, 0, 0); \
        }                                                                             \
        __builtin_amdgcn_s_setprio(0);                                                \
        RELOAD;                                                                       \
    }
#define RELB(BQ, CH)                                                                  \
    {                                                                                 \
        _Pragma("unroll")                                                             \
        for (int n = 0; n < 4; ++n) BQ[n] = *(const i32x4*)(gBr[n] + (CH) * 64);      \
    }

    CHUNK(0, bqA, RELB(bqA, 2))
    CHUNK(1, bqB, RELB(bqB, 3))
    CHUNK(2, bqA, )
    CHUNK(3, bqB, )

    // epilogue: exp(-g*d2) = exp2(K2i*acc - GL*|x|^2 - GL*|y|^2),  K2i = 2*GL*s^2
    // C/D layout: col = lane&15 (fr), row = (lane>>4)*4 + reg  (shape-determined)
    const float GL  = GAMMA * 1.4426950408889634f;   // gamma*log2(e)
    const float K2i = 2.0f * GL * QSCL * QSCL;
    float ncy[4];
    int   gjs[4];
#pragma unroll
    for (int n = 0; n < 4; ++n) {
        gjs[n] = ybase + wc * 64 + n * 16 + fr;
        ncy[n] = -GL * n2[gjs[n]];
    }
    float fsum;
    if (!straddle) {  // strictly above diagonal: uniform weight 2
        float fs0 = 0.f, fs1 = 0.f, fs2 = 0.f, fs3 = 0.f;  // break serial add chain
#pragma unroll
        for (int m = 0; m < 8; ++m) {
#pragma unroll
            for (int j = 0; j < 4; ++j) {
                float cx = GL * n2[xbase + wr * 128 + m * 16 + g * 4 + j];
                fs0 += __builtin_amdgcn_exp2f(fmaf(K2i, (float)acc[m][0][j], ncy[0]) - cx);
                fs1 += __builtin_amdgcn_exp2f(fmaf(K2i, (float)acc[m][1][j], ncy[1]) - cx);
                fs2 += __builtin_amdgcn_exp2f(fmaf(K2i, (float)acc[m][2][j], ncy[2]) - cx);
                fs3 += __builtin_amdgcn_exp2f(fmaf(K2i, (float)acc[m][3][j], ncy[3]) - cx);
            }
        }
        fsum = ((fs0 + fs1) + (fs2 + fs3)) * 2.0f;
    } else {  // diagonal-straddling tile: i<j -> 2, i==j -> 1, i>j -> 0
        fsum = 0.f;
#pragma unroll
        for (int m = 0; m < 8; ++m) {
#pragma unroll
            for (int j = 0; j < 4; ++j) {
                const int gi = xbase + wr * 128 + m * 16 + g * 4 + j;
                float cx = GL * n2[gi];
#pragma unroll
                for (int n = 0; n < 4; ++n) {
                    float e = __builtin_amdgcn_exp2f(fmaf(K2i, (float)acc[m][n][j], ncy[n]) - cx);
                    float wgt = (gi < gjs[n]) ? 2.0f : ((gi == gjs[n]) ? 1.0f : 0.0f);
                    fsum += wgt * e;
                }
            }
        }
    }

#pragma unroll
    for (int off = 32; off; off >>= 1) fsum += __shfl_xor(fsum, off);

    __syncthreads();  // all waves done reading A-LDS before reuse as reduce scratch
    double* wsum = (double*)&lds[0];
    if (l == 0) wsum[w] = (double)fsum;
    __syncthreads();
    if (tid == 0) {
        double tot = wsum[0] + wsum[1] + wsum[2] + wsum[3];
        double sgn = ((xbase < NH) == (ybase < NH)) ? 1.0 : -1.0;
        partial[blockIdx.x] = sgn * tot;
    }
}

// ---------------- final reduce ----------------
__global__ void reduce_partials_kernel(const double* __restrict__ partial,
                                       float* __restrict__ out) {
    __shared__ double ws[4];
    double s = 0.0;
    for (int i = threadIdx.x; i < NTILES; i += 256) s += partial[i];
#pragma unroll
    for (int off = 32; off; off >>= 1) s += __shfl_xor(s, off);
    if ((threadIdx.x & 63) == 0) ws[threadIdx.x >> 6] = s;
    __syncthreads();
    if (threadIdx.x == 0) {
        double tot = ws[0] + ws[1] + ws[2] + ws[3];
        out[0] = (float)(tot / ((double)NH * (double)NH));
    }
}

extern "C" void kernel_launch(void* const* d_in, const int* in_sizes, int n_in,
                              void* d_out, int out_size, void* d_ws, size_t ws_size,
                              hipStream_t stream) {
    const float* zs = (const float*)d_in[0];
    const float* zt = (const float*)d_in[1];
    float* out = (float*)d_out;

    signed char* Zq = (signed char*)d_ws;                        // 4 MB (i8)
    float*  n2      = (float*)((char*)d_ws + 4194304);           // 64 KB
    double* partial = (double*)((char*)d_ws + 4259840);          // 33 KB

    prep_kernel<<<NTOT / 4, 256, 0, stream>>>(zs, zt, Zq, n2);
    mmd_mfma_kernel<<<NTILES, 256, 0, stream>>>(Zq, n2, partial);
    reduce_partials_kernel<<<1, 256, 0, stream>>>(partial, out);
}

// Round 19
// 69.366 us; speedup vs baseline: 1.1360x; 1.1360x over previous
//
#include <hip/hip_runtime.h>

#define NH   8192
#define DIM  256
#define NTOT 16384
#define TM   256                  // tile rows
#define TN   128                  // tile cols
#define NRB  64                   // row blocks
// kept tiles: C >= 2R; F(R) = R*(129-R); total = 4160
#define NTILES 4160
#define FCUM(R) ((R) * (129 - (R)))

constexpr float GAMMA = 0.00390625f; // 1/256
constexpr float QSCL  = 6.0f / 127.0f;   // i8 quant scale: x ~ q * QSCL

using i32x4 = __attribute__((ext_vector_type(4))) int;
using f32x4 = __attribute__((ext_vector_type(4))) float;

// ---------------- fused quantize (fp32 -> i8, s=6/127) + exact fp32 row norms ----------------
__global__ void prep_kernel(const float* __restrict__ zs,
                            const float* __restrict__ zt,
                            signed char* __restrict__ Zq,
                            float* __restrict__ n2) {
    int w = threadIdx.x >> 6, l = threadIdx.x & 63;
    int row = blockIdx.x * 4 + w;
    const float* zp = (row < NH) ? zs + (size_t)row * DIM
                                 : zt + (size_t)(row - NH) * DIM;
    float4 v = *(const float4*)(zp + l * 4);
    float s = v.x * v.x + v.y * v.y + v.z * v.z + v.w * v.w;
#pragma unroll
    for (int off = 32; off; off >>= 1) s += __shfl_xor(s, off);
    if (l == 0) n2[row] = s;

    const float inv = 127.0f / 6.0f;
    float x[4] = {v.x, v.y, v.z, v.w};
    int pk = 0;
#pragma unroll
    for (int j = 0; j < 4; ++j) {
        int q = (int)rintf(fminf(fmaxf(x[j] * inv, -127.0f), 127.0f));
        pk |= (q & 0xFF) << (8 * j);
    }
    *(int*)(Zq + (size_t)row * DIM + l * 4) = pk;
}

// ---------------- main: 256x128 tiles, 4 waves, i8 MFMA (16x16x64) ----------------
// R17 layout/numerics; 2-buffer LDS (48 KB) + depth-1 counted-vmcnt prefetch ->
// 3 blocks/CU = 12 waves/CU (the one axis changed vs R17's 72 KB / 2 blocks).
__global__ __launch_bounds__(256, 3)
void mmd_mfma_kernel(const signed char* __restrict__ Zq,
                     const float* __restrict__ n2,
                     double* __restrict__ partial) {
    // 2 buffers x {A 256x64B, B 128x64B} = 2 x 24 KB = 48 KB
    __shared__ __align__(16) unsigned char lds[2][24576];

    const int tid = threadIdx.x;
    const int w = tid >> 6, l = tid & 63;
    const int wr = w >> 1, wc = w & 1;   // 2x2 wave grid; wave owns 128x64
    const int fr = l & 15;               // fragment row/col within 16
    const int g  = l >> 4;               // k-group 0..3

    // XCD-aware bijective swizzle (4160 % 8 == 0)
    int t = ((int)blockIdx.x & 7) * (NTILES / 8) + ((int)blockIdx.x >> 3);

    // t -> (R, C): largest R with F(R) <= t ; C = 2R + (t - F(R))
    int R = (int)((129.0 - sqrt(129.0 * 129.0 - 4.0 * (double)t)) * 0.5);
    if (R < 0) R = 0;
    if (R > NRB - 1) R = NRB - 1;
    while (R < NRB - 1 && FCUM(R + 1) <= t) ++R;
    while (R > 0 && FCUM(R) > t) --R;
    const int C = 2 * R + (t - FCUM(R));
    const int xbase = R * TM, ybase = C * TN;
    const bool straddle = (C <= 2 * R + 1);  // tile touches/crosses the diagonal

    const signed char* gA = Zq + (size_t)xbase * DIM;
    const signed char* gB = Zq + (size_t)ybase * DIM;

    // fragment reads (bytes): slot' = g ^ ((fr>>1)&3)  (verified conflict-free R2..R18)
    const int slotp = g ^ ((fr >> 1) & 3);
    const int aoff = (wr * 128 + fr) * 64 + slotp * 16;          // + m*1024
    const int boff = 16384 + (wc * 64 + fr) * 64 + slotp * 16;   // + n*1024

    i32x4 acc[8][4];
#pragma unroll
    for (int m = 0; m < 8; ++m)
#pragma unroll
        for (int n = 0; n < 4; ++n) acc[m][n] = {0, 0, 0, 0};

    // staging (bytes): linear LDS dest (tid*16B), pre-swizzled global source slot
    // 6 global_load_lds per thread per STAGE (A: 4, B: 2); KCB = chunk byte offset
#define STAGE(KCB, P)                                                                \
    {                                                                                \
        _Pragma("unroll")                                                            \
        for (int q = 0; q < 4; ++q) { /* A: 1024 x 16B */                            \
            const int idx = q * 256 + tid;                                           \
            const int row = idx >> 2;                                                \
            const int slot = (idx & 3) ^ ((row >> 1) & 3);                           \
            const signed char* src = gA + (size_t)row * DIM + (KCB) + slot * 16;     \
            __builtin_amdgcn_global_load_lds(src, &lds[P][idx * 16], 16, 0, 0);      \
        }                                                                            \
        _Pragma("unroll")                                                            \
        for (int q = 0; q < 2; ++q) { /* B: 512 x 16B */                             \
            const int idx = q * 256 + tid;                                           \
            const int row = idx >> 2;                                                \
            const int slot = (idx & 3) ^ ((row >> 1) & 3);                           \
            const signed char* src = gB + (size_t)row * DIM + (KCB) + slot * 16;     \
            __builtin_amdgcn_global_load_lds(src, &lds[P][16384 + idx * 16], 16, 0, 0);\
        }                                                                            \
    }

    STAGE(0, 0);

#pragma unroll
    for (int ch = 0; ch < 4; ++ch) {  // 4 chunks of K=64
        const int p = ch & 1;
        if (ch < 3) {
            STAGE((ch + 1) * 64, p ^ 1);  // depth-1 prefetch into other buffer
            asm volatile("s_waitcnt vmcnt(6)" ::: "memory");  // chunk ch landed; 6 newer fly
        } else {
            asm volatile("s_waitcnt vmcnt(0)" ::: "memory");
        }
        __builtin_amdgcn_s_barrier();  // all waves' chunk-ch data resident

        i32x4 bq[4];
#pragma unroll
        for (int n = 0; n < 4; ++n) bq[n] = *(const i32x4*)&lds[p][boff + n * 1024];
        __builtin_amdgcn_s_setprio(1);
#pragma unroll
        for (int m = 0; m < 8; ++m) {
            i32x4 aq = *(const i32x4*)&lds[p][aoff + m * 1024];
#pragma unroll
            for (int n = 0; n < 4; ++n)
                acc[m][n] = __builtin_amdgcn_mfma_i32_16x16x64_i8(aq, bq[n], acc[m][n], 0, 0, 0);
        }
        __builtin_amdgcn_s_setprio(0);
        __builtin_amdgcn_s_barrier();  // all waves done reading lds[p] before its rewrite
    }

    // epilogue: exp(-g*d2) = exp2(K2i*acc - GL*|x|^2 - GL*|y|^2),  K2i = 2*GL*s^2
    // C/D layout: col = lane&15 (fr), row = (lane>>4)*4 + reg  (shape-determined)
    const float GL  = GAMMA * 1.4426950408889634f;   // gamma*log2(e)
    const float K2i = 2.0f * GL * QSCL * QSCL;
    float ncy[4];
    int   gjs[4];
#pragma unroll
    for (int n = 0; n < 4; ++n) {
        gjs[n] = ybase + wc * 64 + n * 16 + fr;
        ncy[n] = -GL * n2[gjs[n]];
    }
    float fsum;
    if (!straddle) {  // strictly above diagonal: uniform weight 2
        float fs0 = 0.f, fs1 = 0.f, fs2 = 0.f, fs3 = 0.f;  // break serial add chain
#pragma unroll
        for (int m = 0; m < 8; ++m) {
#pragma unroll
            for (int j = 0; j < 4; ++j) {
                float cx = GL * n2[xbase + wr * 128 + m * 16 + g * 4 + j];
                fs0 += __builtin_amdgcn_exp2f(fmaf(K2i, (float)acc[m][0][j], ncy[0]) - cx);
                fs1 += __builtin_amdgcn_exp2f(fmaf(K2i, (float)acc[m][1][j], ncy[1]) - cx);
                fs2 += __builtin_amdgcn_exp2f(fmaf(K2i, (float)acc[m][2][j], ncy[2]) - cx);
                fs3 += __builtin_amdgcn_exp2f(fmaf(K2i, (float)acc[m][3][j], ncy[3]) - cx);
            }
        }
        fsum = ((fs0 + fs1) + (fs2 + fs3)) * 2.0f;
    } else {  // diagonal-straddling tile: i<j -> 2, i==j -> 1, i>j -> 0
        fsum = 0.f;
#pragma unroll
        for (int m = 0; m < 8; ++m) {
#pragma unroll
            for (int j = 0; j < 4; ++j) {
                const int gi = xbase + wr * 128 + m * 16 + g * 4 + j;
                float cx = GL * n2[gi];
#pragma unroll
                for (int n = 0; n < 4; ++n) {
                    float e = __builtin_amdgcn_exp2f(fmaf(K2i, (float)acc[m][n][j], ncy[n]) - cx);
                    float wgt = (gi < gjs[n]) ? 2.0f : ((gi == gjs[n]) ? 1.0f : 0.0f);
                    fsum += wgt * e;
                }
            }
        }
    }

#pragma unroll
    for (int off = 32; off; off >>= 1) fsum += __shfl_xor(fsum, off);

    __syncthreads();
    double* wsum = (double*)&lds[0][0];
    if (l == 0) wsum[w] = (double)fsum;
    __syncthreads();
    if (tid == 0) {
        double tot = wsum[0] + wsum[1] + wsum[2] + wsum[3];
        double sgn = ((xbase < NH) == (ybase < NH)) ? 1.0 : -1.0;
        partial[blockIdx.x] = sgn * tot;
    }
}

// ---------------- final reduce ----------------
__global__ void reduce_partials_kernel(const double* __restrict__ partial,
                                       float* __restrict__ out) {
    __shared__ double ws[4];
    double s = 0.0;
    for (int i = threadIdx.x; i < NTILES; i += 256) s += partial[i];
#pragma unroll
    for (int off = 32; off; off >>= 1) s += __shfl_xor(s, off);
    if ((threadIdx.x & 63) == 0) ws[threadIdx.x >> 6] = s;
    __syncthreads();
    if (threadIdx.x == 0) {
        double tot = ws[0] + ws[1] + ws[2] + ws[3];
        out[0] = (float)(tot / ((double)NH * (double)NH));
    }
}

extern "C" void kernel_launch(void* const* d_in, const int* in_sizes, int n_in,
                              void* d_out, int out_size, void* d_ws, size_t ws_size,
                              hipStream_t stream) {
    const float* zs = (const float*)d_in[0];
    const float* zt = (const float*)d_in[1];
    float* out = (float*)d_out;

    signed char* Zq = (signed char*)d_ws;                        // 4 MB (i8)
    float*  n2      = (float*)((char*)d_ws + 4194304);           // 64 KB
    double* partial = (double*)((char*)d_ws + 4259840);          // 33 KB

    prep_kernel<<<NTOT / 4, 256, 0, stream>>>(zs, zt, Zq, n2);
    mmd_mfma_kernel<<<NTILES, 256, 0, stream>>>(Zq, n2, partial);
    reduce_partials_kernel<<<1, 256, 0, stream>>>(partial, out);
}